// Round 1
// baseline (1587.427 us; speedup 1.0000x reference)
//
#include <hip/hip_runtime.h>
#include <hip/hip_bf16.h>

#define NS 3200
#define NQ 200000
#define NTOT (NS + NQ)      // 203200
#define KIN 512
#define ED 128
#define NC 64
#define INV_T 1.0f
#define INV_N (1.0f / (float)NTOT)

// ---------------------------------------------------------------------------
// Encoder: out[r][c] = X[r][:] @ W[:][c] + bias[c]
// 64-row x 128-col tile per block, 256 threads, 4x8 micro-tile per thread,
// K staged in LDS chunks of 32.
// ---------------------------------------------------------------------------
__global__ __launch_bounds__(256) void encode_kernel(
    const float* __restrict__ X, const float* __restrict__ W,
    const float* __restrict__ bias, float* __restrict__ out)
{
    __shared__ float Xs[64][36];    // +4 pad, float4-aligned rows
    __shared__ float Ws[32][128];

    const int t = threadIdx.x;
    const int tx = t & 15;          // col group: c0 = 8*tx
    const int ty = t >> 4;          // row group: r0 = 4*ty
    const int c0 = tx * 8;
    const int r0 = ty * 4;
    const long row0 = (long)blockIdx.x * 64;

    float acc[4][8];
#pragma unroll
    for (int j = 0; j < 4; ++j)
#pragma unroll
        for (int i = 0; i < 8; ++i) acc[j][i] = 0.f;

    for (int kk0 = 0; kk0 < KIN; kk0 += 32) {
        // stage X tile: 64 rows x 32 k (coalesced float4)
#pragma unroll
        for (int j = 0; j < 2; ++j) {
            int f4i = t + j * 256;
            int r = f4i >> 3;
            int k0 = (f4i & 7) * 4;
            float4 v = *(const float4*)&X[(row0 + r) * KIN + kk0 + k0];
            *(float4*)&Xs[r][k0] = v;
        }
        // stage W tile: 32 k x 128 c (coalesced float4)
#pragma unroll
        for (int j = 0; j < 4; ++j) {
            int f4i = t + j * 256;
            int k = f4i >> 5;
            int cc = (f4i & 31) * 4;
            *(float4*)&Ws[k][cc] = *(const float4*)&W[(long)(kk0 + k) * ED + cc];
        }
        __syncthreads();
#pragma unroll
        for (int kk = 0; kk < 32; ++kk) {
            float a0 = Xs[r0 + 0][kk];
            float a1 = Xs[r0 + 1][kk];
            float a2 = Xs[r0 + 2][kk];
            float a3 = Xs[r0 + 3][kk];
            float4 w0 = *(const float4*)&Ws[kk][c0];
            float4 w1 = *(const float4*)&Ws[kk][c0 + 4];
            float w[8] = {w0.x, w0.y, w0.z, w0.w, w1.x, w1.y, w1.z, w1.w};
#pragma unroll
            for (int i = 0; i < 8; ++i) {
                acc[0][i] += a0 * w[i];
                acc[1][i] += a1 * w[i];
                acc[2][i] += a2 * w[i];
                acc[3][i] += a3 * w[i];
            }
        }
        __syncthreads();
    }

    float bb[8];
#pragma unroll
    for (int i = 0; i < 8; ++i) bb[i] = bias[c0 + i];
#pragma unroll
    for (int j = 0; j < 4; ++j) {
        float4 o0 = make_float4(acc[j][0] + bb[0], acc[j][1] + bb[1],
                                acc[j][2] + bb[2], acc[j][3] + bb[3]);
        float4 o1 = make_float4(acc[j][4] + bb[4], acc[j][5] + bb[5],
                                acc[j][6] + bb[6], acc[j][7] + bb[7]);
        *(float4*)&out[(row0 + r0 + j) * ED + c0] = o0;
        *(float4*)&out[(row0 + r0 + j) * ED + c0 + 4] = o1;
    }
}

// ---------------------------------------------------------------------------
// Initial prototypes: per-class mean of support embeddings.
// One block per class (64), 128 threads = one per embedding dim.
// ---------------------------------------------------------------------------
__global__ __launch_bounds__(128) void proto_init_kernel(
    const float* __restrict__ s_emb, const int* __restrict__ labels,
    float* __restrict__ proto)
{
    const int c = blockIdx.x;
    const int d = threadIdx.x;
    float acc = 0.f;
    int cnt = 0;
    for (int r = 0; r < NS; ++r) {
        int lbl = labels[r];          // uniform across block -> scalar load
        if (lbl == c) {
            acc += s_emb[(long)r * ED + d];
            cnt++;
        }
    }
    proto[c * ED + d] = acc / fmaxf((float)cnt, 1.0f);
}

// ---------------------------------------------------------------------------
// Fused propagation step:
//   attn = softmax(-||e_r - p_c|| / T) over c,  accum[c][d] += attn[r][c]*e[r][d]
// proto read as proto_src * proto_scale (scale folds the 1/n_total division).
// 512 threads, 32-row tiles, grid-stride; per-thread 4x4 proto accumulator,
// one atomicAdd per element per block at the end.
// ---------------------------------------------------------------------------
__global__ __launch_bounds__(512) void propagate_kernel(
    const float* __restrict__ emb,
    const float* __restrict__ proto_src,
    float proto_scale,
    float* __restrict__ accum)
{
    __shared__ float PT[128][64];     // transposed scaled proto: PT[d][c]
    __shared__ float Es[32][132];     // row-major emb tile (+4 pad)
    __shared__ float Sc[32 * 65];     // attn tile, stride 65 (conflict-free)
    __shared__ float en2[32];
    __shared__ float pn2[64];

    const int t = threadIdx.x;

    // stage scaled transposed prototypes
    for (int idx = t; idx < NC * ED; idx += 512) {
        int c = idx & (NC - 1);
        int d = idx >> 6;
        PT[d][c] = proto_src[c * ED + d] * proto_scale;
    }
    __syncthreads();
    if (t < NC) {
        float s = 0.f;
#pragma unroll 8
        for (int d = 0; d < ED; ++d) { float v = PT[d][t]; s += v * v; }
        pn2[t] = s;
    }
    __syncthreads();

    const int tx = t & 15;            // score phase: c0 = 4*tx
    const int rown = t >> 4;          // score phase: row 0..31
    const int c0 = tx * 4;
    const int td = t & 31;            // accum phase: d0 = 4*td
    const int tc = t >> 5;            // accum phase: c0a = 4*tc
    const int d0 = td * 4;
    const int c0a = tc * 4;
    const int rA = t >> 5;            // staging: rows rA, rA+16
    const int j4 = (t & 31) * 4;

    float pacc[4][4];
#pragma unroll
    for (int i = 0; i < 4; ++i)
#pragma unroll
        for (int j = 0; j < 4; ++j) pacc[i][j] = 0.f;

    const int ntiles = NTOT / 32;
    for (int tile = blockIdx.x; tile < ntiles; tile += gridDim.x) {
        const long row0 = (long)tile * 32;

        // stage emb tile + row norms (norm partials reduced over half-wave)
        float4 vA = *(const float4*)&emb[(row0 + rA) * ED + j4];
        float4 vB = *(const float4*)&emb[(row0 + rA + 16) * ED + j4];
        *(float4*)&Es[rA][j4] = vA;
        *(float4*)&Es[rA + 16][j4] = vB;
        float pA = vA.x * vA.x + vA.y * vA.y + vA.z * vA.z + vA.w * vA.w;
        float pB = vB.x * vB.x + vB.y * vB.y + vB.z * vB.z + vB.w * vB.w;
#pragma unroll
        for (int m = 1; m <= 16; m <<= 1) {
            pA += __shfl_xor(pA, m);
            pB += __shfl_xor(pB, m);
        }
        if ((t & 31) == 0) { en2[rA] = pA; en2[rA + 16] = pB; }
        __syncthreads();

        // score phase: dots of my row against classes c0..c0+3
        float dot0 = 0.f, dot1 = 0.f, dot2 = 0.f, dot3 = 0.f;
        const float* esrow = &Es[rown][0];
#pragma unroll 8
        for (int d = 0; d < ED; ++d) {
            float e = esrow[d];
            float4 p = *(const float4*)&PT[d][c0];
            dot0 += e * p.x; dot1 += e * p.y; dot2 += e * p.z; dot3 += e * p.w;
        }
        float en = en2[rown];
        float s0 = -sqrtf(fmaxf(en + pn2[c0 + 0] - 2.f * dot0, 0.f)) * INV_T;
        float s1 = -sqrtf(fmaxf(en + pn2[c0 + 1] - 2.f * dot1, 0.f)) * INV_T;
        float s2 = -sqrtf(fmaxf(en + pn2[c0 + 2] - 2.f * dot2, 0.f)) * INV_T;
        float s3 = -sqrtf(fmaxf(en + pn2[c0 + 3] - 2.f * dot3, 0.f)) * INV_T;

        // softmax over 64 classes = reduce across the row's 16 contiguous lanes
        float mx = fmaxf(fmaxf(s0, s1), fmaxf(s2, s3));
#pragma unroll
        for (int m = 1; m <= 8; m <<= 1) mx = fmaxf(mx, __shfl_xor(mx, m));
        float e0 = __expf(s0 - mx), e1 = __expf(s1 - mx);
        float e2 = __expf(s2 - mx), e3 = __expf(s3 - mx);
        float ps = e0 + e1 + e2 + e3;
#pragma unroll
        for (int m = 1; m <= 8; m <<= 1) ps += __shfl_xor(ps, m);
        float inv = 1.f / ps;
        Sc[rown * 65 + c0 + 0] = e0 * inv;
        Sc[rown * 65 + c0 + 1] = e1 * inv;
        Sc[rown * 65 + c0 + 2] = e2 * inv;
        Sc[rown * 65 + c0 + 3] = e3 * inv;
        __syncthreads();

        // accumulate proto update: pacc[ci][di] += attn[r][c0a+ci] * E[r][d0+di]
#pragma unroll 4
        for (int r = 0; r < 32; ++r) {
            float4 ev = *(const float4*)&Es[r][d0];
            float a0 = Sc[r * 65 + c0a + 0];
            float a1 = Sc[r * 65 + c0a + 1];
            float a2 = Sc[r * 65 + c0a + 2];
            float a3 = Sc[r * 65 + c0a + 3];
            pacc[0][0] += a0 * ev.x; pacc[0][1] += a0 * ev.y;
            pacc[0][2] += a0 * ev.z; pacc[0][3] += a0 * ev.w;
            pacc[1][0] += a1 * ev.x; pacc[1][1] += a1 * ev.y;
            pacc[1][2] += a1 * ev.z; pacc[1][3] += a1 * ev.w;
            pacc[2][0] += a2 * ev.x; pacc[2][1] += a2 * ev.y;
            pacc[2][2] += a2 * ev.z; pacc[2][3] += a2 * ev.w;
            pacc[3][0] += a3 * ev.x; pacc[3][1] += a3 * ev.y;
            pacc[3][2] += a3 * ev.z; pacc[3][3] += a3 * ev.w;
        }
        __syncthreads();
    }

#pragma unroll
    for (int ci = 0; ci < 4; ++ci)
#pragma unroll
        for (int di = 0; di < 4; ++di)
            atomicAdd(&accum[(c0a + ci) * ED + d0 + di], pacc[ci][di]);
}

// ---------------------------------------------------------------------------
// Final logits: out[q][c] = -||q_emb - proto[c]|| / T  (pre-softmax scores)
// ---------------------------------------------------------------------------
__global__ __launch_bounds__(512) void logits_kernel(
    const float* __restrict__ emb,        // q_emb base
    const float* __restrict__ proto_src,
    float proto_scale,
    float* __restrict__ out)
{
    __shared__ float PT[128][64];
    __shared__ float Es[32][132];
    __shared__ float en2[32];
    __shared__ float pn2[64];

    const int t = threadIdx.x;

    for (int idx = t; idx < NC * ED; idx += 512) {
        int c = idx & (NC - 1);
        int d = idx >> 6;
        PT[d][c] = proto_src[c * ED + d] * proto_scale;
    }
    __syncthreads();
    if (t < NC) {
        float s = 0.f;
#pragma unroll 8
        for (int d = 0; d < ED; ++d) { float v = PT[d][t]; s += v * v; }
        pn2[t] = s;
    }
    __syncthreads();

    const int tx = t & 15;
    const int rown = t >> 4;
    const int c0 = tx * 4;
    const int rA = t >> 5;
    const int j4 = (t & 31) * 4;

    const int ntiles = NQ / 32;
    for (int tile = blockIdx.x; tile < ntiles; tile += gridDim.x) {
        const long row0 = (long)tile * 32;

        float4 vA = *(const float4*)&emb[(row0 + rA) * ED + j4];
        float4 vB = *(const float4*)&emb[(row0 + rA + 16) * ED + j4];
        *(float4*)&Es[rA][j4] = vA;
        *(float4*)&Es[rA + 16][j4] = vB;
        float pA = vA.x * vA.x + vA.y * vA.y + vA.z * vA.z + vA.w * vA.w;
        float pB = vB.x * vB.x + vB.y * vB.y + vB.z * vB.z + vB.w * vB.w;
#pragma unroll
        for (int m = 1; m <= 16; m <<= 1) {
            pA += __shfl_xor(pA, m);
            pB += __shfl_xor(pB, m);
        }
        if ((t & 31) == 0) { en2[rA] = pA; en2[rA + 16] = pB; }
        __syncthreads();

        float dot0 = 0.f, dot1 = 0.f, dot2 = 0.f, dot3 = 0.f;
        const float* esrow = &Es[rown][0];
#pragma unroll 8
        for (int d = 0; d < ED; ++d) {
            float e = esrow[d];
            float4 p = *(const float4*)&PT[d][c0];
            dot0 += e * p.x; dot1 += e * p.y; dot2 += e * p.z; dot3 += e * p.w;
        }
        float en = en2[rown];
        float s0 = -sqrtf(fmaxf(en + pn2[c0 + 0] - 2.f * dot0, 0.f)) * INV_T;
        float s1 = -sqrtf(fmaxf(en + pn2[c0 + 1] - 2.f * dot1, 0.f)) * INV_T;
        float s2 = -sqrtf(fmaxf(en + pn2[c0 + 2] - 2.f * dot2, 0.f)) * INV_T;
        float s3 = -sqrtf(fmaxf(en + pn2[c0 + 3] - 2.f * dot3, 0.f)) * INV_T;

        *(float4*)&out[(row0 + rown) * NC + c0] = make_float4(s0, s1, s2, s3);
        __syncthreads();
    }
}

// ---------------------------------------------------------------------------
extern "C" void kernel_launch(void* const* d_in, const int* in_sizes, int n_in,
                              void* d_out, int out_size, void* d_ws, size_t ws_size,
                              hipStream_t stream)
{
    (void)in_sizes; (void)n_in; (void)out_size; (void)ws_size;

    const float* support = (const float*)d_in[0];   // [1, NS, KIN]
    const float* query   = (const float*)d_in[1];   // [1, NQ, KIN]
    const int*   labels  = (const int*)d_in[2];     // [NS]
    const float* W       = (const float*)d_in[3];   // [KIN, ED]
    const float* bias    = (const float*)d_in[4];   // [ED]
    float* out = (float*)d_out;                     // [1, NQ, NC]

    // workspace layout (floats)
    float* emb    = (float*)d_ws;                   // [NTOT][ED] (support, then query)
    float* proto0 = emb + (size_t)NTOT * ED;        // [NC][ED]
    float* accA   = proto0 + (size_t)NC * ED;       // [NC][ED]
    float* accB   = accA + (size_t)NC * ED;         // [NC][ED]

    // embeddings
    encode_kernel<<<NS / 64, 256, 0, stream>>>(support, W, bias, emb);
    encode_kernel<<<NQ / 64, 256, 0, stream>>>(query, W, bias, emb + (size_t)NS * ED);

    // initial prototypes (segment mean of support embeddings)
    proto_init_kernel<<<NC, ED, 0, stream>>>(emb, labels, proto0);

    // 3 propagation steps; scale folds the /n_total into the proto read
    hipMemsetAsync(accA, 0, NC * ED * sizeof(float), stream);
    propagate_kernel<<<512, 512, 0, stream>>>(emb, proto0, 1.0f, accA);

    hipMemsetAsync(accB, 0, NC * ED * sizeof(float), stream);
    propagate_kernel<<<512, 512, 0, stream>>>(emb, accA, INV_N, accB);

    hipMemsetAsync(accA, 0, NC * ED * sizeof(float), stream);
    propagate_kernel<<<512, 512, 0, stream>>>(emb, accB, INV_N, accA);

    // final logits over query rows with proto_3
    logits_kernel<<<512, 512, 0, stream>>>(emb + (size_t)NS * ED, accA, INV_N, out);
}

// Round 2
// 888.806 us; speedup vs baseline: 1.7860x; 1.7860x over previous
//
#include <hip/hip_runtime.h>

#define NS 3200
#define NQ 200000
#define NTOT (NS + NQ)      // 203200 = 64 * 3175
#define KIN 512
#define ED 128
#define NC 64
#define INV_N (1.0f / (float)NTOT)

typedef short short8 __attribute__((ext_vector_type(8)));
typedef short short4v __attribute__((ext_vector_type(4)));
typedef float floatx4 __attribute__((ext_vector_type(4)));

static __device__ __forceinline__ unsigned short f2bf(float f) {
    unsigned int u = __float_as_uint(f);
    u += 0x7FFF + ((u >> 16) & 1);          // round-to-nearest-even
    return (unsigned short)(u >> 16);
}
static __device__ __forceinline__ float bf2f(unsigned short h) {
    return __uint_as_float(((unsigned int)h) << 16);
}

// ---------------------------------------------------------------------------
// One-time: WTbf[n][k] = bf16(W[k][n])   (128 x 512)
// ---------------------------------------------------------------------------
__global__ __launch_bounds__(256) void prep_wt(const float* __restrict__ W,
                                               unsigned short* __restrict__ WT)
{
    int idx = blockIdx.x * 256 + threadIdx.x;
#pragma unroll
    for (int p = 0; p < 4; ++p) {
        int id = idx + p * 16384;          // 64 blocks * 256 thr * 4 = 65536
        int n = id >> 9, k = id & 511;
        WT[n * 512 + k] = f2bf(W[k * 128 + n]);
    }
}

// ---------------------------------------------------------------------------
// Encoder: emb[r][c] = bf16( X[r][:] @ W[:,c] + bias[c] ),  en2[r] = ||emb_r||^2
// 64-row x 128-col tile, 256 thr (4 waves), MFMA 16x16x32 bf16, K staged by 64.
// ---------------------------------------------------------------------------
__global__ __launch_bounds__(256) void encode_mfma(
    const float* __restrict__ X, const unsigned short* __restrict__ WT,
    const float* __restrict__ bias, unsigned short* __restrict__ emb,
    float* __restrict__ en2)
{
    __shared__ unsigned short Xs[64 * 72];   // [row][k], stride 72 (bank-spread)
    __shared__ unsigned short Ws[128 * 72];  // [n][k],  stride 72

    const int t = threadIdx.x;
    const int w = t >> 6;
    const int lane = t & 63;
    const int q = lane >> 4;
    const int i = lane & 15;
    const long row0 = (long)blockIdx.x * 64;

    floatx4 acc[8];
#pragma unroll
    for (int ct = 0; ct < 8; ++ct) acc[ct] = (floatx4){0.f, 0.f, 0.f, 0.f};

    for (int kk0 = 0; kk0 < KIN; kk0 += 64) {
        // stage X tile 64x64 fp32 -> bf16 (coalesced float4 reads)
#pragma unroll
        for (int p = 0; p < 4; ++p) {
            int id = p * 256 + t;
            int r = id >> 4, kf4 = id & 15;
            float4 v = *(const float4*)&X[(row0 + r) * KIN + kk0 + kf4 * 4];
            short4v h;
            h[0] = (short)f2bf(v.x); h[1] = (short)f2bf(v.y);
            h[2] = (short)f2bf(v.z); h[3] = (short)f2bf(v.w);
            *(short4v*)&Xs[r * 72 + kf4 * 4] = h;
        }
        // stage W tile 128x64 bf16 (16B copies)
#pragma unroll
        for (int p = 0; p < 4; ++p) {
            int id = p * 256 + t;
            int n = id >> 3, ch = id & 7;
            uint4 v = *(const uint4*)&WT[n * 512 + kk0 + ch * 8];
            *(uint4*)&Ws[n * 72 + ch * 8] = v;
        }
        __syncthreads();
#pragma unroll
        for (int ks = 0; ks < 2; ++ks) {
            short8 a = *(const short8*)&Xs[(w * 16 + i) * 72 + ks * 32 + q * 8];
#pragma unroll
            for (int ct = 0; ct < 8; ++ct) {
                short8 b = *(const short8*)&Ws[(ct * 16 + i) * 72 + ks * 32 + q * 8];
                acc[ct] = __builtin_amdgcn_mfma_f32_16x16x32_bf16(a, b, acc[ct], 0, 0, 0);
            }
        }
        __syncthreads();
    }

    // epilogue: bias, store bf16, row norms
    float sq[4] = {0.f, 0.f, 0.f, 0.f};
#pragma unroll
    for (int ct = 0; ct < 8; ++ct) {
        float bb = bias[ct * 16 + i];
#pragma unroll
        for (int r = 0; r < 4; ++r) {
            float v = acc[ct][r] + bb;
            long row = row0 + w * 16 + q * 4 + r;
            emb[row * ED + ct * 16 + i] = f2bf(v);
            sq[r] += v * v;
        }
    }
#pragma unroll
    for (int r = 0; r < 4; ++r) {
        float s = sq[r];
        s += __shfl_xor(s, 1); s += __shfl_xor(s, 2);
        s += __shfl_xor(s, 4); s += __shfl_xor(s, 8);
        if (i == 0) en2[row0 + w * 16 + q * 4 + r] = s;
    }
}

// ---------------------------------------------------------------------------
// Initial prototypes: per-class mean of support embeddings.
// ---------------------------------------------------------------------------
__global__ __launch_bounds__(128) void proto_init(
    const unsigned short* __restrict__ emb, const int* __restrict__ labels,
    float* __restrict__ proto)
{
    const int c = blockIdx.x, d = threadIdx.x;
    float acc = 0.f; int cnt = 0;
    for (int r4 = 0; r4 < NS; r4 += 4) {
        int4 lb = *(const int4*)&labels[r4];
        if (lb.x == c) { acc += bf2f(emb[(r4 + 0) * ED + d]); cnt++; }
        if (lb.y == c) { acc += bf2f(emb[(r4 + 1) * ED + d]); cnt++; }
        if (lb.z == c) { acc += bf2f(emb[(r4 + 2) * ED + d]); cnt++; }
        if (lb.w == c) { acc += bf2f(emb[(r4 + 3) * ED + d]); cnt++; }
    }
    proto[c * ED + d] = acc / fmaxf((float)cnt, 1.0f);
}

// ---------------------------------------------------------------------------
// Fused propagation: S = E @ P^T (MFMA) -> softmax (regs) -> P' += A^T @ E (MFMA)
// 256 thr (4 waves), 64-row tiles, grid-stride, accum in regs + atomics at end.
// ---------------------------------------------------------------------------
__global__ __launch_bounds__(256) void propagate(
    const unsigned short* __restrict__ emb, const float* __restrict__ en2,
    const float* __restrict__ proto_src, float scale,
    float* __restrict__ accum)
{
    __shared__ unsigned short Pbf[64 * 136];  // [class][d], stride 136
    __shared__ unsigned short ET[128 * 66];   // [d][row],   stride 66 (b16-write spread)
    __shared__ unsigned short ScT[64 * 72];   // [class][row], stride 72
    __shared__ float pn2s[64];

    const int t = threadIdx.x;
    const int w = t >> 6, lane = t & 63, q = lane >> 4, i = lane & 15;

    // prototype prep: scale, bf16, norms
    {
        int c = t >> 2, part = t & 3;
        const float* src = &proto_src[c * 128 + part * 32];
        float sqv = 0.f;
#pragma unroll 8
        for (int j = 0; j < 32; ++j) {
            float v = src[j] * scale;
            Pbf[c * 136 + part * 32 + j] = f2bf(v);
            sqv += v * v;
        }
        sqv += __shfl_xor(sqv, 1);
        sqv += __shfl_xor(sqv, 2);
        if (part == 0) pn2s[c] = sqv;
    }
    __syncthreads();

    // hoist B-fragments (prototypes) + pn to registers — constant over tiles
    short8 bP[4][4];
#pragma unroll
    for (int ct = 0; ct < 4; ++ct)
#pragma unroll
        for (int ks = 0; ks < 4; ++ks)
            bP[ct][ks] = *(const short8*)&Pbf[(ct * 16 + i) * 136 + ks * 32 + q * 8];
    float pn[4];
#pragma unroll
    for (int ct = 0; ct < 4; ++ct) pn[ct] = pn2s[ct * 16 + i];

    floatx4 acc2[8];
#pragma unroll
    for (int nt = 0; nt < 8; ++nt) acc2[nt] = (floatx4){0.f, 0.f, 0.f, 0.f};

    const int ntiles = NTOT / 64;
    for (int tile = blockIdx.x; tile < ntiles; tile += gridDim.x) {
        const long row0 = (long)tile * 64;

        // A-fragments straight from global bf16 emb (16B/lane)
        short8 aE[4];
#pragma unroll
        for (int ks = 0; ks < 4; ++ks)
            aE[ks] = *(const short8*)&emb[(row0 + w * 16 + i) * ED + ks * 32 + q * 8];
        float en[4];
#pragma unroll
        for (int r = 0; r < 4; ++r) en[r] = en2[row0 + w * 16 + q * 4 + r];

        // transpose E tile into LDS for GEMM2 B-operand
#pragma unroll
        for (int ks = 0; ks < 4; ++ks)
#pragma unroll
            for (int j = 0; j < 8; ++j)
                ET[(ks * 32 + q * 8 + j) * 66 + w * 16 + i] = (unsigned short)aE[ks][j];

        // GEMM1: S[16 rows x 64 classes]
        floatx4 s1[4];
#pragma unroll
        for (int ct = 0; ct < 4; ++ct) s1[ct] = (floatx4){0.f, 0.f, 0.f, 0.f};
#pragma unroll
        for (int ks = 0; ks < 4; ++ks)
#pragma unroll
            for (int ct = 0; ct < 4; ++ct)
                s1[ct] = __builtin_amdgcn_mfma_f32_16x16x32_bf16(aE[ks], bP[ct][ks], s1[ct], 0, 0, 0);

        // softmax over 64 classes (4 cts in regs x 16 lanes of quad)
        float attn[4][4];   // [ct][r]
#pragma unroll
        for (int r = 0; r < 4; ++r) {
            float sc[4];
#pragma unroll
            for (int ct = 0; ct < 4; ++ct) {
                float d2 = en[r] + pn[ct] - 2.f * s1[ct][r];
                sc[ct] = -sqrtf(fmaxf(d2, 0.f));
            }
            float mx = fmaxf(fmaxf(sc[0], sc[1]), fmaxf(sc[2], sc[3]));
            mx = fmaxf(mx, __shfl_xor(mx, 1));
            mx = fmaxf(mx, __shfl_xor(mx, 2));
            mx = fmaxf(mx, __shfl_xor(mx, 4));
            mx = fmaxf(mx, __shfl_xor(mx, 8));
            float sm = 0.f;
#pragma unroll
            for (int ct = 0; ct < 4; ++ct) { attn[ct][r] = __expf(sc[ct] - mx); sm += attn[ct][r]; }
            sm += __shfl_xor(sm, 1);
            sm += __shfl_xor(sm, 2);
            sm += __shfl_xor(sm, 4);
            sm += __shfl_xor(sm, 8);
            float inv = 1.f / sm;
#pragma unroll
            for (int ct = 0; ct < 4; ++ct) attn[ct][r] *= inv;
        }
        // write attn transposed: ScT[class][row] (4 rows packed per b64 write)
#pragma unroll
        for (int ct = 0; ct < 4; ++ct) {
            short4v pk;
            pk[0] = (short)f2bf(attn[ct][0]); pk[1] = (short)f2bf(attn[ct][1]);
            pk[2] = (short)f2bf(attn[ct][2]); pk[3] = (short)f2bf(attn[ct][3]);
            *(short4v*)&ScT[(ct * 16 + i) * 72 + w * 16 + q * 4] = pk;
        }
        __syncthreads();

        // GEMM2: wave w -> classes w*16..+15, all 128 dims, K = 64 rows
#pragma unroll
        for (int ks2 = 0; ks2 < 2; ++ks2) {
            short8 a2 = *(const short8*)&ScT[(w * 16 + i) * 72 + ks2 * 32 + q * 8];
#pragma unroll
            for (int nt = 0; nt < 8; ++nt) {
                union { short8 s; unsigned int u[4]; } b2;
                const unsigned short* base = &ET[(nt * 16 + i) * 66 + ks2 * 32 + q * 8];
                b2.u[0] = *(const unsigned int*)&base[0];
                b2.u[1] = *(const unsigned int*)&base[2];
                b2.u[2] = *(const unsigned int*)&base[4];
                b2.u[3] = *(const unsigned int*)&base[6];
                acc2[nt] = __builtin_amdgcn_mfma_f32_16x16x32_bf16(a2, b2.s, acc2[nt], 0, 0, 0);
            }
        }
        __syncthreads();
    }

#pragma unroll
    for (int nt = 0; nt < 8; ++nt)
#pragma unroll
        for (int r = 0; r < 4; ++r)
            atomicAdd(&accum[(w * 16 + q * 4 + r) * ED + nt * 16 + i], acc2[nt][r]);
}

// ---------------------------------------------------------------------------
// Final logits: out[q][c] = -sqrt(max(||e||^2 + ||p||^2 - 2 e.p, 0))
// GEMM1-only variant of propagate.
// ---------------------------------------------------------------------------
__global__ __launch_bounds__(256) void logits_k(
    const unsigned short* __restrict__ emb, const float* __restrict__ en2,
    const float* __restrict__ proto_src, float scale, float* __restrict__ out)
{
    __shared__ unsigned short Pbf[64 * 136];
    __shared__ float pn2s[64];

    const int t = threadIdx.x;
    const int w = t >> 6, lane = t & 63, q = lane >> 4, i = lane & 15;

    {
        int c = t >> 2, part = t & 3;
        const float* src = &proto_src[c * 128 + part * 32];
        float sqv = 0.f;
#pragma unroll 8
        for (int j = 0; j < 32; ++j) {
            float v = src[j] * scale;
            Pbf[c * 136 + part * 32 + j] = f2bf(v);
            sqv += v * v;
        }
        sqv += __shfl_xor(sqv, 1);
        sqv += __shfl_xor(sqv, 2);
        if (part == 0) pn2s[c] = sqv;
    }
    __syncthreads();

    short8 bP[4][4];
#pragma unroll
    for (int ct = 0; ct < 4; ++ct)
#pragma unroll
        for (int ks = 0; ks < 4; ++ks)
            bP[ct][ks] = *(const short8*)&Pbf[(ct * 16 + i) * 136 + ks * 32 + q * 8];
    float pn[4];
#pragma unroll
    for (int ct = 0; ct < 4; ++ct) pn[ct] = pn2s[ct * 16 + i];

    const int ntiles = NQ / 64;
    for (int tile = blockIdx.x; tile < ntiles; tile += gridDim.x) {
        const long row0 = (long)tile * 64;

        short8 aE[4];
#pragma unroll
        for (int ks = 0; ks < 4; ++ks)
            aE[ks] = *(const short8*)&emb[(row0 + w * 16 + i) * ED + ks * 32 + q * 8];
        float en[4];
#pragma unroll
        for (int r = 0; r < 4; ++r) en[r] = en2[row0 + w * 16 + q * 4 + r];

        floatx4 s1[4];
#pragma unroll
        for (int ct = 0; ct < 4; ++ct) s1[ct] = (floatx4){0.f, 0.f, 0.f, 0.f};
#pragma unroll
        for (int ks = 0; ks < 4; ++ks)
#pragma unroll
            for (int ct = 0; ct < 4; ++ct)
                s1[ct] = __builtin_amdgcn_mfma_f32_16x16x32_bf16(aE[ks], bP[ct][ks], s1[ct], 0, 0, 0);

#pragma unroll
        for (int r = 0; r < 4; ++r) {
            long row = row0 + w * 16 + q * 4 + r;
#pragma unroll
            for (int ct = 0; ct < 4; ++ct) {
                float d2 = en[r] + pn[ct] - 2.f * s1[ct][r];
                out[row * NC + ct * 16 + i] = -sqrtf(fmaxf(d2, 0.f));
            }
        }
    }
}

// ---------------------------------------------------------------------------
extern "C" void kernel_launch(void* const* d_in, const int* in_sizes, int n_in,
                              void* d_out, int out_size, void* d_ws, size_t ws_size,
                              hipStream_t stream)
{
    (void)in_sizes; (void)n_in; (void)out_size; (void)ws_size;

    const float* support = (const float*)d_in[0];
    const float* query   = (const float*)d_in[1];
    const int*   labels  = (const int*)d_in[2];
    const float* W       = (const float*)d_in[3];
    const float* bias    = (const float*)d_in[4];
    float* out = (float*)d_out;

    unsigned short* emb = (unsigned short*)d_ws;                 // [NTOT][128] bf16
    float* en2 = (float*)(emb + (size_t)NTOT * ED);              // [NTOT]
    unsigned short* WT = (unsigned short*)(en2 + NTOT);          // [128][512] bf16
    float* proto0 = (float*)(WT + 128 * 512);                    // [64][128]
    float* accA = proto0 + NC * ED;
    float* accB = accA + NC * ED;

    prep_wt<<<64, 256, 0, stream>>>(W, WT);
    encode_mfma<<<NS / 64, 256, 0, stream>>>(support, WT, bias, emb, en2);
    encode_mfma<<<NQ / 64, 256, 0, stream>>>(query, WT, bias,
                                             emb + (size_t)NS * ED, en2 + NS);
    proto_init<<<NC, ED, 0, stream>>>(emb, labels, proto0);

    hipMemsetAsync(accA, 0, NC * ED * sizeof(float), stream);
    propagate<<<512, 256, 0, stream>>>(emb, en2, proto0, 1.0f, accA);

    hipMemsetAsync(accB, 0, NC * ED * sizeof(float), stream);
    propagate<<<512, 256, 0, stream>>>(emb, en2, accA, INV_N, accB);

    hipMemsetAsync(accA, 0, NC * ED * sizeof(float), stream);
    propagate<<<512, 256, 0, stream>>>(emb, en2, accB, INV_N, accA);

    logits_k<<<1024, 256, 0, stream>>>(emb + (size_t)NS * ED, en2 + NS,
                                       accA, INV_N, out);
}